// Round 1
// baseline (337.031 us; speedup 1.0000x reference)
//
#include <hip/hip_runtime.h>
#include <stdint.h>

#define B_    4
#define N_    2048
#define D_    4096
#define E_    64
#define TOKENS (B_ * N_)        // 8192
#define KT    32                // K-tile staged in LDS
#define TM    128               // tokens per block tile
#define KS    8                 // split-K factor (DO NOT CHANGE: logit bit-exactness)
#define KCHUNK (D_ / KS)        // 512
#define NITER (KCHUNK / KT)     // 16

typedef float vfloat4 __attribute__((ext_vector_type(4)));  // native vec for NT stores

// global -> LDS direct DMA, 16B per lane, wave-uniform LDS base + lane*16
#define GL2LDS16(g, s) __builtin_amdgcn_global_load_lds(                     \
    (const __attribute__((address_space(1))) void*)(g),                      \
    (__attribute__((address_space(3))) void*)(s), 16, 0, 0)

// ---------------------------------------------------------------------------
// K1: split-K fp32 GEMM fused with d_out zero-fill.
// 128 threads (2 waves), tile 128 tok x 64 experts, thread tile 8x8.
// LDS-instruction-throughput redesign:
//   - 8x8 per-thread tile: 4 ds_read_b128 per 64 FMA (was 2 per 16) -> halves
//     LDS read traffic, the measured bottleneck.
//   - global_load_lds width=16 for both A and W: zero ds_write instructions,
//     no VGPR round trip. A stored untransposed [tok][32] (DMA-linear rows);
//     the 16B slot is XOR-swizzled with (tok>>3)&7 on the GLOBAL source side
//     (rule 21: linear dest + inverse-swizzled source + swizzled read)
//     -> conflict-free b128 fragment reads.
//   - double-buffered LDS (48 KB, 2 blocks/CU): DMA for tile k+1 issued
//     before compute of tile k; single barrier per iter drains vmcnt after
//     ~5k cycles of FMA/LDS work.
// Accumulation order per (token,expert,kc) is unchanged (ascending k, fp32
// fmac) -> logits bit-identical to previous passing kernel.
// Each block also streams its 20480-float4 slice of d_out as zeros (NT),
// interleaved with the K-loop. Block 0 zeroes probsum + the two loss slots.
// ---------------------------------------------------------------------------
__global__ __launch_bounds__(128) void k_gemm_z(const float* __restrict__ A,
                                                const float* __restrict__ W,
                                                float* __restrict__ P,
                                                float* __restrict__ out,
                                                float* __restrict__ probsum,
                                                float* __restrict__ losses) {
    __shared__ float As[2][TM][KT];   // [tok][16B-slot swizzled], DMA-linear
    __shared__ float Ws[2][KT][E_];   // global-contiguous tile, DMA-linear

    const int tid   = threadIdx.x;
    const int l     = tid & 63;        // lane
    const int w     = tid >> 6;        // wave 0..1
    const int tok0  = blockIdx.x * TM;
    const int kc    = blockIdx.y;
    const int kbase = kc * KCHUNK;
    const int blin  = kc * gridDim.x + blockIdx.x;   // 0..511

    const int t0 = (tid >> 3) * 8;     // token offset 0..120
    const int e0 = (tid & 7) * 8;      // expert offset 0..56
    const int sw = (tid >> 3) & 7;     // read-side swizzle key = (tok>>3)&7

    // --- DMA source pointers (advance by KT each iter) ---------------------
    // A: issue i covers tokens i*8..i*8+7; lane l -> tok i*8+(l>>3), slot l&7;
    //    source k-chunk = (slot ^ (i&7)) so LDS[tok][slot] holds k4 = slot^((tok>>3)&7)
    const float* pA[8];
    #pragma unroll
    for (int q = 0; q < 8; ++q) {
        const int i  = w * 8 + q;
        const int tk = i * 8 + (l >> 3);
        const int ks = (l & 7) ^ (i & 7);
        pA[q] = A + (size_t)(tok0 + tk) * D_ + kbase + ks * 4;
    }
    // W: tile is 8 KB contiguous in global; issue i covers rows i*4..i*4+3
    const float* pW[4];
    #pragma unroll
    for (int q = 0; q < 4; ++q) {
        const int i  = w * 4 + q;
        const int kk = i * 4 + (l >> 4);
        pW[q] = W + (size_t)(kbase + kk) * E_ + (l & 15) * 4;
    }

    // zero-fill: block covers float4 range [blin*20480, (blin+1)*20480)
    vfloat4* zbase = reinterpret_cast<vfloat4*>(out) + (size_t)blin * 20480 + tid;
    const vfloat4 z4 = {0.f, 0.f, 0.f, 0.f};

    if (blin == 0) {
        probsum[tid] = 0.f;            // 256 entries, 128 threads
        probsum[tid + 128] = 0.f;
        if (tid < 2) losses[tid] = 0.f;
    }

    // prologue: stage tile 0 into buf 0
    #pragma unroll
    for (int q = 0; q < 8; ++q) {
        GL2LDS16(pA[q], &As[0][(w * 8 + q) * 8][0]);
        pA[q] += KT;
    }
    #pragma unroll
    for (int q = 0; q < 4; ++q) {
        GL2LDS16(pW[q], &Ws[0][(w * 4 + q) * 4][0]);
        pW[q] += KT * E_;
    }
    __syncthreads();                   // vmcnt(0) drain -> buf0 ready

    float acc[8][8];
    #pragma unroll
    for (int i = 0; i < 8; ++i)
        #pragma unroll
        for (int j = 0; j < 8; ++j) acc[i][j] = 0.f;

    #pragma unroll 1
    for (int kt = 0; kt < NITER; ++kt) {
        const int cur = kt & 1;
        const int nxt = cur ^ 1;

        // issue next-tile DMA first: whole compute phase hides the latency
        if (kt + 1 < NITER) {
            #pragma unroll
            for (int q = 0; q < 8; ++q) {
                GL2LDS16(pA[q], &As[nxt][(w * 8 + q) * 8][0]);
                pA[q] += KT;
            }
            #pragma unroll
            for (int q = 0; q < 4; ++q) {
                GL2LDS16(pW[q], &Ws[nxt][(w * 4 + q) * 4][0]);
                pW[q] += KT * E_;
            }
        }

        // interleaved zero stores: 10/iter * 16 iters = 160 = 20480/128
        #pragma unroll
        for (int j = 0; j < 10; ++j)
            __builtin_nontemporal_store(z4, zbase + (size_t)(kt * 10 + j) * 128);

        #pragma unroll
        for (int kk4 = 0; kk4 < 8; ++kk4) {
            float4 av[8];
            const int so = ((kk4 ^ sw) << 2);   // swizzled 16B slot
            #pragma unroll
            for (int i = 0; i < 8; ++i)
                av[i] = *reinterpret_cast<const float4*>(&As[cur][t0 + i][so]);
            #pragma unroll
            for (int k = 0; k < 4; ++k) {       // kk = kt*KT + kk4*4 + k, ascending
                const float4 w0 = *reinterpret_cast<const float4*>(&Ws[cur][kk4 * 4 + k][e0]);
                const float4 w1 = *reinterpret_cast<const float4*>(&Ws[cur][kk4 * 4 + k][e0 + 4]);
                #pragma unroll
                for (int i = 0; i < 8; ++i) {
                    const float a = (k == 0) ? av[i].x : (k == 1) ? av[i].y
                                  : (k == 2) ? av[i].z : av[i].w;
                    acc[i][0] += a * w0.x; acc[i][1] += a * w0.y;
                    acc[i][2] += a * w0.z; acc[i][3] += a * w0.w;
                    acc[i][4] += a * w1.x; acc[i][5] += a * w1.y;
                    acc[i][6] += a * w1.z; acc[i][7] += a * w1.w;
                }
            }
        }
        __syncthreads();               // drains this iter's DMA for next iter
    }

    float* base = P + ((size_t)kc * TOKENS + tok0) * E_;
    #pragma unroll
    for (int i = 0; i < 8; ++i) {
        *reinterpret_cast<float4*>(&base[(size_t)(t0 + i) * E_ + e0]) =
            make_float4(acc[i][0], acc[i][1], acc[i][2], acc[i][3]);
        *reinterpret_cast<float4*>(&base[(size_t)(t0 + i) * E_ + e0 + 4]) =
            make_float4(acc[i][4], acc[i][5], acc[i][6], acc[i][7]);
    }
}

// ---------------------------------------------------------------------------
// K2: reduce split-K partials; per-token softmax stats (wave per token, lane =
// expert). Writes argmax idx, gate (=max prob), accumulates probsum[b][e] and
// the z-loss (atomic, pre-scaled). UNCHANGED (isolating the K1 change).
// ---------------------------------------------------------------------------
__global__ __launch_bounds__(256) void k_softmax(const float* __restrict__ P,
                                                 int* __restrict__ idx,
                                                 float* __restrict__ gate,
                                                 float* __restrict__ probsum,
                                                 float* __restrict__ out_z) {
    const int tid  = threadIdx.x;
    const int wid  = tid >> 6;
    const int lane = tid & 63;
    const int tok  = blockIdx.x * 4 + wid;

    float l = 0.f;
    #pragma unroll
    for (int kc = 0; kc < KS; ++kc)
        l += P[((size_t)kc * TOKENS + tok) * E_ + lane];

    // wave argmax, first-index tie-break (matches numpy)
    float m = l; int mi = lane;
    #pragma unroll
    for (int off = 32; off > 0; off >>= 1) {
        const float om = __shfl_down(m, off);
        const int   oi = __shfl_down(mi, off);
        if (om > m || (om == m && oi < mi)) { m = om; mi = oi; }
    }
    m  = __shfl(m, 0);
    mi = __shfl(mi, 0);

    const float p = __expf(l - m);
    float s = p;
    #pragma unroll
    for (int off = 32; off > 0; off >>= 1) s += __shfl_down(s, off);
    s = __shfl(s, 0);

    __shared__ float pacc[4][E_];
    __shared__ float zv[4];
    pacc[wid][lane] = p / s;
    if (lane == 0) {
        const float lse = m + logf(s);
        zv[wid]   = lse * lse;
        idx[tok]  = mi;
        gate[tok] = 1.0f / s;                 // exp(m-m)/s = max prob
    }
    __syncthreads();

    if (tid < E_) {
        const float ps = pacc[0][tid] + pacc[1][tid] + pacc[2][tid] + pacc[3][tid];
        const int b = (blockIdx.x * 4) / N_;  // block never crosses batch
        atomicAdd(&probsum[b * E_ + tid], ps);
    }
    if (tid == 0)
        atomicAdd(out_z, (zv[0] + zv[1] + zv[2] + zv[3]) * (1.0f / (float)TOKENS));
}

// ---------------------------------------------------------------------------
// K3: ordered position-in-expert via wave ballot (matches reference cumsum),
// scatter into dispatch/combine + aux-loss fused. One wave per (b,e).
// UNCHANGED.
// ---------------------------------------------------------------------------
__global__ __launch_bounds__(64) void k_posloss(const int* __restrict__ idx,
                                                const float* __restrict__ gate,
                                                const float* __restrict__ probsum,
                                                float* __restrict__ out,
                                                float* __restrict__ out_aux,
                                                int C, size_t half) {
    const int b = blockIdx.x >> 6;
    const int e = blockIdx.x & 63;
    const int lane = threadIdx.x;
    const int*   ib = idx  + b * N_;
    const float* gb = gate + b * N_;
    float* ob = out + (size_t)b * N_ * E_ * C;   // dispatch base for batch b

    int running = 0;
    for (int step = 0; step < N_ / 64; ++step) {
        const int t = step * 64 + lane;
        const bool match = (ib[t] == e);
        const unsigned long long mask = __ballot(match);
        if (match) {
            const int p = running + __popcll(mask & ((1ull << lane) - 1ull));
            if (p < C) {
                const size_t off = (size_t)t * E_ * C + (size_t)e * C + p;
                ob[off] = 1.0f;            // dispatch
                ob[half + off] = gb[t];    // combine
            }
        }
        running += __popcll(mask);
    }
    if (lane == 0)   // aux = sum(count * probsum) * E^2/(B*E*N*N) = sum/262144
        atomicAdd(out_aux,
                  (float)running * probsum[b * E_ + e] * (1.0f / 262144.0f));
}

// ---------------------------------------------------------------------------
extern "C" void kernel_launch(void* const* d_in, const int* in_sizes, int n_in,
                              void* d_out, int out_size, void* d_ws, size_t ws_size,
                              hipStream_t stream) {
    const float* A = (const float*)d_in[0];
    const float* W = (const float*)d_in[1];
    float* out = (float*)d_out;

    const size_t half = ((size_t)out_size - 2) / 2;          // TOKENS*E*C
    const int C = (int)(half / ((size_t)TOKENS * E_));       // 40

    float* P = (float*)d_ws;
    size_t off = (size_t)KS * TOKENS * E_;
    int*   idx     = (int*)(P + off);   off += TOKENS;
    float* gate    = P + off;           off += TOKENS;
    float* probsum = P + off;           off += B_ * E_;

    float* out_aux = out + 2 * half;
    float* out_z   = out + 2 * half + 1;

    // k_gemm_z zeroes all of d_out (2*half floats via per-block NT-store
    // slices; 2*half = 41,943,040 floats = 512 blocks * 20480 float4 exactly)
    // plus probsum and the two loss scalars (block 0). No hipMemsetAsync.
    k_gemm_z<<<dim3(TOKENS / TM, KS), 128, 0, stream>>>(A, W, P, out, probsum,
                                                        out_aux);
    k_softmax<<<TOKENS / 4, 256, 0, stream>>>(P, idx, gate, probsum, out_z);
    k_posloss<<<B_ * E_, 64, 0, stream>>>(idx, gate, probsum, out, out_aux, C, half);
}